// Round 1
// baseline (183.437 us; speedup 1.0000x reference)
//
#include <hip/hip_runtime.h>
#include <math.h>

// Fixed problem shape (ResonanceRotaryEmbedding): B=2, H=16, L=8192, DIM=128
#define BB   2
#define LL   8192
#define DIMM 128
#define D2   64

// seq_len = max(position_ids) + 1, single-block reduction -> d_ws[0]
__global__ void seqlen_kernel(const int* __restrict__ pos, int n, int* __restrict__ out) {
    int t = threadIdx.x;
    int m = -2147483647 - 1;
    for (int i = t; i < n; i += 256) m = max(m, pos[i]);
    #pragma unroll
    for (int off = 32; off > 0; off >>= 1)
        m = max(m, __shfl_down(m, off, 64));
    __shared__ int smem[4];
    if ((t & 63) == 0) smem[t >> 6] = m;
    __syncthreads();
    if (t == 0) {
        int r = max(max(smem[0], smem[1]), max(smem[2], smem[3]));
        out[0] = r + 1;
    }
}

// One thread per (b, l, d) with d in [0, 64). Lanes 0..63 cover d 0..63 for a
// single l -> every global store is a fully-coalesced 64-lane dword store.
__global__ void rope_kernel(const int* __restrict__ pos_ids,
                            const float* __restrict__ inv_freq,
                            const float* __restrict__ wavelengths,
                            const int* __restrict__ seq_len_p,
                            float* __restrict__ out) {
    int tid = blockIdx.x * blockDim.x + threadIdx.x;   // BB*LL*D2 threads
    int d = tid & (D2 - 1);
    int l = (tid >> 6) & (LL - 1);
    int b = tid >> 19;                                  // 6 + 13 bits

    int seq_len = seq_len_p[0];
    int w = (int)wavelengths[d];
    float fi = inv_freq[d];

    int widx = (w <= seq_len) ? (l % w) : l;
    float p = (float)pos_ids[b * LL + widx];
    float ang = p * fi;                                 // always < 2*pi
    float s = __sinf(ang);
    float c = __cosf(ang);

    float* cosb = out;
    float* sinb = out + (size_t)BB * LL * DIMM;
    size_t base = (size_t)b * LL * DIMM + (size_t)l * DIMM + d;
    cosb[base]      = c;
    cosb[base + D2] = c;
    sinb[base]      = s;
    sinb[base + D2] = s;
}

extern "C" void kernel_launch(void* const* d_in, const int* in_sizes, int n_in,
                              void* d_out, int out_size, void* d_ws, size_t ws_size,
                              hipStream_t stream) {
    // inputs: 0=x (unused, fp32), 1=position_ids (int32 [B,L]),
    //         2=r_inv_freq (fp32 [64]), 3=r_wavelengths (fp32 [64])
    const int*   pos  = (const int*)d_in[1];
    const float* finv = (const float*)d_in[2];
    const float* wav  = (const float*)d_in[3];
    float* out = (float*)d_out;
    int*   ws  = (int*)d_ws;

    int n_pos = in_sizes[1];
    seqlen_kernel<<<1, 256, 0, stream>>>(pos, n_pos, ws);

    int total = BB * LL * D2;
    rope_kernel<<<total / 256, 256, 0, stream>>>(pos, finv, wav, ws, out);
}

// Round 2
// 173.047 us; speedup vs baseline: 1.0600x; 1.0600x over previous
//
#include <hip/hip_runtime.h>
#include <math.h>

// Fixed problem shape (ResonanceRotaryEmbedding): B=2, H=16, L=8192, DIM=128
#define BB   2
#define LL   8192
#define DIMM 128
#define D2   64

#define NBLOCKS 256
#define NTHREADS 256

// Fused: per-block seq_len reduction (redundant across blocks -> no cross-block
// deps) + wave-per-row cos/sin emission with float2 coalesced stores.
__global__ void __launch_bounds__(NTHREADS)
rope_fused_kernel(const int* __restrict__ pos_ids, int n_pos,
                  const float* __restrict__ inv_freq,
                  const float* __restrict__ wavelengths,
                  float* __restrict__ out) {
    const int t = threadIdx.x;

    // ---- per-block seq_len = max(pos_ids) + 1 ----
    int m = -2147483647 - 1;
    const int n4 = n_pos >> 2;                 // 16384 / 4 = 4096 int4 loads
    const int4* p4 = (const int4*)pos_ids;
    for (int i = t; i < n4; i += NTHREADS) {   // 16 iters, independent loads
        int4 v = p4[i];
        m = max(max(m, v.x), max(max(v.y, v.z), v.w));
    }
    for (int i = (n4 << 2) + t; i < n_pos; i += NTHREADS) m = max(m, pos_ids[i]);
    #pragma unroll
    for (int off = 32; off > 0; off >>= 1)
        m = max(m, __shfl_down(m, off, 64));
    __shared__ int smem[NTHREADS / 64];
    __shared__ int s_seqlen;
    if ((t & 63) == 0) smem[t >> 6] = m;
    __syncthreads();
    if (t == 0) {
        int r = smem[0];
        #pragma unroll
        for (int i = 1; i < NTHREADS / 64; i++) r = max(r, smem[i]);
        s_seqlen = r + 1;
    }
    __syncthreads();
    const int seq_len = s_seqlen;

    // ---- per-lane loop-invariant setup: lane i covers columns 2i, 2i+1 ----
    const int lane = t & 63;
    const int wv   = t >> 6;                       // wave id in block (0..3)
    const int d0 = (2 * lane) & (D2 - 1);          // lanes 0-31: d=0..63; 32-63: repeat
    const int d1 = d0 + 1;
    const int w0 = (int)wavelengths[d0];
    const int w1 = (int)wavelengths[d1];
    const float f0 = inv_freq[d0];
    const float f1 = inv_freq[d1];
    const bool mod0 = (w0 <= seq_len);
    const bool mod1 = (w1 <= seq_len);

    // ---- rows: global wave id covers ROWS/NWAVES consecutive rows ----
    const int gw = blockIdx.x * (NTHREADS / 64) + wv;     // 0..1023
    const int NWAVES = NBLOCKS * (NTHREADS / 64);         // 1024
    const int ROWS = BB * LL;                             // 16384
    const int rpw = ROWS / NWAVES;                        // 16

    float2* cosb = (float2*)out;
    float2* sinb = (float2*)(out + (size_t)BB * LL * DIMM);

    #pragma unroll 4
    for (int k = 0; k < rpw; k++) {
        const int r = gw * rpw + k;
        const int b = r >> 13;                 // r / LL
        const int l = r & (LL - 1);

        const int i0 = mod0 ? (l % w0) : l;
        const int i1 = mod1 ? (l % w1) : l;
        const float p0 = (float)pos_ids[b * LL + i0];
        const float p1 = (float)pos_ids[b * LL + i1];
        const float a0 = p0 * f0;              // < 2*pi always
        const float a1 = p1 * f1;

        const size_t rowbase = ((size_t)r * DIMM >> 1) + lane;  // float2 units
        cosb[rowbase] = make_float2(__cosf(a0), __cosf(a1));
        sinb[rowbase] = make_float2(__sinf(a0), __sinf(a1));
    }
}

extern "C" void kernel_launch(void* const* d_in, const int* in_sizes, int n_in,
                              void* d_out, int out_size, void* d_ws, size_t ws_size,
                              hipStream_t stream) {
    // inputs: 0=x (unused, fp32), 1=position_ids (int32 [B,L]),
    //         2=r_inv_freq (fp32 [64]), 3=r_wavelengths (fp32 [64])
    const int*   pos  = (const int*)d_in[1];
    const float* finv = (const float*)d_in[2];
    const float* wav  = (const float*)d_in[3];
    float* out = (float*)d_out;

    rope_fused_kernel<<<NBLOCKS, NTHREADS, 0, stream>>>(pos, in_sizes[1], finv, wav, out);
}